// Round 2
// baseline (1376.817 us; speedup 1.0000x reference)
//
#include <hip/hip_runtime.h>

// BEiT attention block, fp16 MFMA pipeline.
// Stages: cvt(x,W) -> gemm_qkv(scatter q,k,v^T padded) -> attn -> gemm_proj.
typedef _Float16 f16_t;
typedef _Float16 f16x8 __attribute__((ext_vector_type(8)));
typedef float f32x4 __attribute__((ext_vector_type(4)));

#define MFMA_F16(a, b, c) __builtin_amdgcn_mfma_f32_16x16x32_f16(a, b, c, 0, 0, 0)

__device__ __forceinline__ void gll16(const void* g, void* l) {
  __builtin_amdgcn_global_load_lds(
      (__attribute__((address_space(1))) void*)(const_cast<void*>(g)),
      (__attribute__((address_space(3))) void*)(l), 16, 0, 0);
}

// ---------------- fp32 -> fp16 convert (8 elems/thread) ----------------
__global__ __launch_bounds__(256) void k_cvt(const float* __restrict__ in,
                                             f16_t* __restrict__ out, int n8) {
  int i = blockIdx.x * 256 + threadIdx.x;
  if (i >= n8) return;
  f32x4 a = ((const f32x4*)in)[2 * i];
  f32x4 b = ((const f32x4*)in)[2 * i + 1];
  f16x8 o;
  o[0] = (f16_t)a[0]; o[1] = (f16_t)a[1]; o[2] = (f16_t)a[2]; o[3] = (f16_t)a[3];
  o[4] = (f16_t)b[0]; o[5] = (f16_t)b[1]; o[6] = (f16_t)b[2]; o[7] = (f16_t)b[3];
  ((f16x8*)out)[i] = o;
}

// ---------------- gather rel-pos bias -> [12][197][197] fp32 ----------------
__global__ __launch_bounds__(256) void k_gather_bias(const float* __restrict__ tab,
                                                     const int* __restrict__ idx,
                                                     float* __restrict__ out, int total) {
  int i = blockIdx.x * 256 + threadIdx.x;
  if (i >= total) return;
  int h = i / 38809;
  int ij = i - h * 38809;
  out[i] = tab[idx[ij] * 12 + h];
}

// ---------------- 128x128 BT-GEMM, K=768, BK=32, fp16 MFMA ----------------
// EPI 0: qkv epilogue (scatter q*scale+qb, k, (v+vb)^T). EPI 1: proj (+bias, fp32 out).
template <int EPI>
__global__ __launch_bounds__(256) void k_gemm(
    const f16_t* __restrict__ A, const f16_t* __restrict__ Bw,
    const float* __restrict__ qb, const float* __restrict__ vbias,
    f16_t* __restrict__ oq, f16_t* __restrict__ okk, f16_t* __restrict__ ov,
    float* __restrict__ of, int nbn) {
  __shared__ f16_t sA[2][4096];
  __shared__ f16_t sB[2][4096];
  const int tid = threadIdx.x, lane = tid & 63, wid = tid >> 6;
  const int c16 = lane & 15, g4 = lane >> 4;
  const int wr = wid >> 1, wc = wid & 1;
  const int bn = blockIdx.x % nbn, bm = blockIdx.x / nbn;
  const int swz = (g4 ^ ((c16 >> 1) & 3)) * 8;  // element offset of 16B seg, 2-way banks

  f32x4 acc[4][4];
#pragma unroll
  for (int m = 0; m < 4; ++m)
#pragma unroll
    for (int n = 0; n < 4; ++n) acc[m][n] = f32x4{0.f, 0.f, 0.f, 0.f};

  // staging geometry: 512 16B-units per matrix; wave w owns chunks 2w, 2w+1
  const int U0 = wid * 128 + lane, U1 = U0 + 64;
  const int r0 = U0 >> 2, s0 = (U0 & 3) ^ ((r0 >> 1) & 3);
  const int r1 = U1 >> 2, s1 = (U1 & 3) ^ ((r1 >> 1) & 3);
  const char* gA0 = (const char*)A + (size_t)(bm * 128 + r0) * 1536 + s0 * 16;
  const char* gA1 = (const char*)A + (size_t)(bm * 128 + r1) * 1536 + s1 * 16;
  const char* gB0 = (const char*)Bw + (size_t)(bn * 128 + r0) * 1536 + s0 * 16;
  const char* gB1 = (const char*)Bw + (size_t)(bn * 128 + r1) * 1536 + s1 * 16;
  char* lA = (char*)&sA[0][0] + wid * 2048;
  char* lB = (char*)&sB[0][0] + wid * 2048;

  auto stage = [&](int buf, int ks) {
    size_t ko = (size_t)ks * 64, bo = (size_t)buf * 8192;
    gll16(gA0 + ko, lA + bo);
    gll16(gA1 + ko, lA + bo + 1024);
    gll16(gB0 + ko, lB + bo);
    gll16(gB1 + ko, lB + bo + 1024);
  };
  auto compute = [&](int buf) {
    const f16_t* bA = &sA[buf][0];
    const f16_t* bB = &sB[buf][0];
    f16x8 av[4], bv[4];
#pragma unroll
    for (int m = 0; m < 4; ++m) {
      av[m] = *(const f16x8*)(bA + (wr * 64 + m * 16 + c16) * 32 + swz);
      bv[m] = *(const f16x8*)(bB + (wc * 64 + m * 16 + c16) * 32 + swz);
    }
#pragma unroll
    for (int m = 0; m < 4; ++m)
#pragma unroll
      for (int n = 0; n < 4; ++n) acc[m][n] = MFMA_F16(av[m], bv[n], acc[m][n]);
  };

  stage(0, 0);
  __syncthreads();
  int cur = 0;
  for (int ks = 1; ks < 24; ++ks) {  // K=768 -> 24 steps of 32
    stage(cur ^ 1, ks);
    compute(cur);
    __syncthreads();
    cur ^= 1;
  }
  compute(cur);

  if (EPI == 0) {
#pragma unroll
    for (int nt = 0; nt < 4; ++nt) {
      const int gn = bn * 128 + wc * 64 + nt * 16 + c16;
      const int which = (gn >= 1536) ? 2 : (gn >= 768 ? 1 : 0);
      const int wn = gn - which * 768;
      const int h = wn >> 6, d = wn & 63;
      const float bq = qb[wn], bv_ = vbias[wn];
#pragma unroll
      for (int mt = 0; mt < 4; ++mt) {
#pragma unroll
        for (int r = 0; r < 4; ++r) {
          const int gm = bm * 128 + wr * 64 + mt * 16 + g4 * 4 + r;
          const int b = gm / 197, tok = gm - b * 197;
          const int bh = b * 12 + h;
          float v = acc[mt][nt][r];
          if (which == 0)
            oq[((size_t)bh * 208 + tok) * 64 + d] = (f16_t)((v + bq) * 0.125f);
          else if (which == 1)
            okk[((size_t)bh * 208 + tok) * 64 + d] = (f16_t)v;
          else
            ov[((size_t)bh * 64 + d) * 256 + tok] = (f16_t)(v + bv_);
        }
      }
    }
  } else {
#pragma unroll
    for (int nt = 0; nt < 4; ++nt) {
      const int gn = bn * 128 + wc * 64 + nt * 16 + c16;
      const float pb = qb[gn];
#pragma unroll
      for (int mt = 0; mt < 4; ++mt)
#pragma unroll
        for (int r = 0; r < 4; ++r) {
          const int gm = bm * 128 + wr * 64 + mt * 16 + g4 * 4 + r;
          of[(size_t)gm * 768 + gn] = acc[mt][nt][r] + pb;
        }
    }
  }
}

// ---------------- attention: 1 block per (b,h), 4 waves over 13 M-tiles ----------------
__global__ __launch_bounds__(256) void k_attn(
    const f16_t* __restrict__ qg, const f16_t* __restrict__ kg,
    const f16_t* __restrict__ vt, const float* __restrict__ bg,
    f16_t* __restrict__ ao) {
  __shared__ f16_t sk[208 * 64];   // K, swizzled units
  __shared__ f16_t sv[64 * 256];   // V^T, swizzled units
  __shared__ f16_t sp[4][16 * 256];  // per-wave P tile
  const int tid = threadIdx.x, lane = tid & 63, wid = tid >> 6;
  const int c16 = lane & 15, g4 = lane >> 4;
  const int bh = blockIdx.x, b = bh / 12, h = bh - b * 12;

  for (int c = wid; c < 26; c += 4) {  // K: 208 rows x 8 units
    const int U = c * 64 + lane, key = U >> 3, u = U & 7, su = u ^ (key & 7);
    gll16((const char*)kg + (size_t)bh * 26624 + key * 128 + su * 16, (char*)sk + (size_t)c * 1024);
  }
  for (int c = wid; c < 32; c += 4) {  // V^T: 64 rows x 32 units
    const int U = c * 64 + lane, d = U >> 5, u = U & 31, su = u ^ (d & 7);
    gll16((const char*)vt + (size_t)bh * 32768 + d * 512 + su * 16, (char*)sv + (size_t)c * 1024);
  }
  f16_t* pw = &sp[wid][0];
  for (int i = lane; i < 96; i += 64) {  // zero P units 26..31 (tokens 208..255)
    const int row = i / 6, u = 26 + (i - (i / 6) * 6);
    *(f32x4*)(pw + row * 256 + ((u ^ (row & 7)) << 3)) = f32x4{0.f, 0.f, 0.f, 0.f};
  }
  __syncthreads();

  const float* bptr = bg + (size_t)h * 38809;

  for (int mt = wid; mt < 13; mt += 4) {
    const f16_t* qrow = qg + ((size_t)bh * 208 + mt * 16 + c16) * 64 + g4 * 8;
    const f16x8 qa0 = *(const f16x8*)qrow;
    const f16x8 qa1 = *(const f16x8*)(qrow + 32);

    f32x4 s[13];
#pragma unroll
    for (int t = 0; t < 13; ++t) {
      const int key = t * 16 + c16;
      const f16x8 kb0 = *(const f16x8*)(sk + key * 64 + ((g4 ^ (key & 7)) << 3));
      const f16x8 kb1 = *(const f16x8*)(sk + key * 64 + (((4 + g4) ^ (key & 7)) << 3));
      f32x4 z = {0.f, 0.f, 0.f, 0.f};
      z = MFMA_F16(qa0, kb0, z);
      z = MFMA_F16(qa1, kb1, z);
      s[t] = z;
    }

    const int tokbase = mt * 16 + g4 * 4;
#pragma unroll
    for (int t = 0; t < 13; ++t) {
      const int key = t * 16 + c16;
#pragma unroll
      for (int r = 0; r < 4; ++r) {
        const int tok = tokbase + r;
        const bool ok2 = (key < 197) && (tok < 197);
        const float bvv = bptr[ok2 ? tok * 197 + key : 0];
        s[t][r] = ok2 ? (s[t][r] + bvv) : -1e30f;
      }
    }

    float inv[4];
#pragma unroll
    for (int r = 0; r < 4; ++r) {
      float m = s[0][r];
#pragma unroll
      for (int t = 1; t < 13; ++t) m = fmaxf(m, s[t][r]);
      m = fmaxf(m, __shfl_xor(m, 1));
      m = fmaxf(m, __shfl_xor(m, 2));
      m = fmaxf(m, __shfl_xor(m, 4));
      m = fmaxf(m, __shfl_xor(m, 8));
      float sum = 0.f;
#pragma unroll
      for (int t = 0; t < 13; ++t) {
        float e = __expf(s[t][r] - m);
        s[t][r] = e;
        sum += e;
      }
      sum += __shfl_xor(sum, 1);
      sum += __shfl_xor(sum, 2);
      sum += __shfl_xor(sum, 4);
      sum += __shfl_xor(sum, 8);
      inv[r] = 1.f / sum;
    }

#pragma unroll
    for (int t = 0; t < 13; ++t) {
      const int col = t * 16 + c16, u = col >> 3;
#pragma unroll
      for (int r = 0; r < 4; ++r) {
        const int row = g4 * 4 + r;
        pw[row * 256 + ((u ^ (row & 7)) << 3) + (col & 7)] = (f16_t)(s[t][r] * inv[r]);
      }
    }

    f16x8 pa[7];
#pragma unroll
    for (int kc = 0; kc < 7; ++kc) {
      const int u = kc * 4 + g4;
      pa[kc] = *(const f16x8*)(pw + c16 * 256 + ((u ^ (c16 & 7)) << 3));
    }

#pragma unroll
    for (int dt = 0; dt < 4; ++dt) {
      const int d = dt * 16 + c16;
      f32x4 o = {0.f, 0.f, 0.f, 0.f};
#pragma unroll
      for (int kc = 0; kc < 7; ++kc) {
        const f16x8 vv = *(const f16x8*)(sv + d * 256 + (((kc * 4 + g4) ^ (d & 7)) << 3));
        o = MFMA_F16(pa[kc], vv, o);
      }
#pragma unroll
      for (int r = 0; r < 4; ++r) {
        const int tok = tokbase + r;
        if (tok < 197)
          ao[((size_t)(b * 197 + tok)) * 768 + h * 64 + dt * 16 + c16] = (f16_t)o[r];
      }
    }
  }
}

extern "C" void kernel_launch(void* const* d_in, const int* in_sizes, int n_in,
                              void* d_out, int out_size, void* d_ws, size_t ws_size,
                              hipStream_t stream) {
  const float* x = (const float*)d_in[0];
  const float* qkv_w = (const float*)d_in[1];
  const float* q_bias = (const float*)d_in[2];
  const float* v_bias = (const float*)d_in[3];
  const float* reltab = (const float*)d_in[4];
  const float* proj_w = (const float*)d_in[5];
  const float* proj_b = (const float*)d_in[6];
  const int* relidx = (const int*)d_in[7];
  float* out = (float*)d_out;

  char* p = (char*)d_ws;
  auto take = [&](size_t bytes) {
    char* r = p;
    p += (bytes + 255) & ~(size_t)255;
    return r;
  };
  f16_t* x_h = (f16_t*)take(50432ull * 768 * 2);     // also reused as attn-out
  f16_t* qw_h = (f16_t*)take(2304ull * 768 * 2);
  f16_t* pw_h = (f16_t*)take(768ull * 768 * 2);
  float* bg = (float*)take(12ull * 38809 * 4);
  f16_t* q_g = (f16_t*)take(3072ull * 208 * 64 * 2);
  f16_t* k_g = (f16_t*)take(3072ull * 208 * 64 * 2);
  f16_t* v_t = (f16_t*)take(3072ull * 64 * 256 * 2);
  f16_t* ao = x_h;  // x_h dead after qkv GEMM; alias to save workspace

  const int n8_x = 50432 * 768 / 8;      // 4,841,472
  const int n8_qw = 2304 * 768 / 8;      // 221,184
  const int n8_pw = 768 * 768 / 8;       // 73,728
  k_cvt<<<dim3((n8_x + 255) / 256), dim3(256), 0, stream>>>(x, x_h, n8_x);
  k_cvt<<<dim3((n8_qw + 255) / 256), dim3(256), 0, stream>>>(qkv_w, qw_h, n8_qw);
  k_cvt<<<dim3((n8_pw + 255) / 256), dim3(256), 0, stream>>>(proj_w, pw_h, n8_pw);
  k_gather_bias<<<dim3((12 * 38809 + 255) / 256), dim3(256), 0, stream>>>(reltab, relidx, bg, 12 * 38809);
  k_gemm<0><<<dim3(394 * 18), dim3(256), 0, stream>>>(x_h, qw_h, q_bias, v_bias,
                                                      q_g, k_g, v_t, nullptr, 18);
  k_attn<<<dim3(3072), dim3(256), 0, stream>>>(q_g, k_g, v_t, bg, ao);
  k_gemm<1><<<dim3(394 * 6), dim3(256), 0, stream>>>(ao, pw_h, proj_b, nullptr,
                                                     nullptr, nullptr, nullptr, out, 6);
}